// Round 1
// baseline (315.570 us; speedup 1.0000x reference)
//
#include <hip/hip_runtime.h>
#include <hip/hip_bf16.h>
#include <stdint.h>

typedef __attribute__((ext_vector_type(4))) float f32x4;
typedef __attribute__((ext_vector_type(8))) __bf16 bf16x8;
typedef __attribute__((ext_vector_type(4))) __bf16 bf16x4;

#define LN_EPS 1e-5f

// ---------------- helpers ----------------
__device__ __forceinline__ void gload_lds16(const void* g, void* l) {
  __builtin_amdgcn_global_load_lds(
      (__attribute__((address_space(1))) void*)(uintptr_t)g,
      (__attribute__((address_space(3))) void*)(uint32_t)(uintptr_t)l,
      16, 0, 0);
}

__device__ __forceinline__ f32x4 mfma16(bf16x8 a, bf16x8 b, f32x4 c) {
  return __builtin_amdgcn_mfma_f32_16x16x32_bf16(a, b, c, 0, 0, 0);
}

// ---------------- prep kernels ----------------
__global__ __launch_bounds__(256) void k_cvt_bf16(const float* __restrict__ x,
                                                  __bf16* __restrict__ o) {
  int i = (blockIdx.x * 256 + threadIdx.x) * 8;
  f32x4 a = *(const f32x4*)(x + i);
  f32x4 b = *(const f32x4*)(x + i + 4);
  bf16x8 v;
#pragma unroll
  for (int j = 0; j < 4; ++j) { v[j] = (__bf16)a[j]; v[j + 4] = (__bf16)b[j]; }
  *(bf16x8*)(o + i) = v;
}

// W [K][N] f32 -> Wt [N][K] bf16
__global__ void k_transpose(const float* __restrict__ W, __bf16* __restrict__ Wt,
                            int K, int N) {
  __shared__ float t[32][33];
  int nt = blockIdx.x * 32, kt = blockIdx.y * 32;
  int tx = threadIdx.x, ty = threadIdx.y;
  t[ty][tx] = W[(size_t)(kt + ty) * N + nt + tx];
  __syncthreads();
  Wt[(size_t)(nt + ty) * K + kt + tx] = (__bf16)t[tx][ty];
}

// centered log-embedding: log(E*256) (argmax-invariant shift keeps bf16 resolution)
__global__ __launch_bounds__(256) void k_logE(const float* __restrict__ e,
                                              __bf16* __restrict__ o) {
  int i = blockIdx.x * 256 + threadIdx.x;
  o[i] = (__bf16)logf(e[i] * 256.0f);
}

// ---------------- GEMM: C[M][N] = A[M][K] * Bt[N][K]^T ----------------
// 128x128 tile, BK=64, 4 waves (2x2), 16x16x32 bf16 MFMA, global_load_lds(16B),
// XOR-swizzled LDS (byte ^= (row&7)<<4) applied on the *global source* side
// (linear LDS dest, rule #21) and on the ds_read side.
// EPI: 0 = bf16 store, 1 = f32 + bias store, 2 = per-row argmax partials
template <int EPI>
__global__ __launch_bounds__(256) void k_gemm(
    const __bf16* __restrict__ A, const __bf16* __restrict__ Bt,
    void* __restrict__ outp, const float* __restrict__ bias,
    float* __restrict__ part_val, int* __restrict__ part_idx,
    int N, int K) {
  __shared__ char lds[32768];
  char* ldsA = lds;
  char* ldsB = lds + 16384;
  const int tid = threadIdx.x;
  const int lane = tid & 63;
  const int wid = tid >> 6;
  const int wm = wid >> 1, wn = wid & 1;
  const int bm0 = blockIdx.x * 128;
  const int bn0 = blockIdx.y * 128;

  const int slin = tid * 16;                         // linear LDS byte offset
  const int srow = slin >> 7;                        // tile row (per 128B row)
  const int scol = (slin & 127) ^ ((srow & 7) << 4); // pre-swizzled source col

  const char* Ab = (const char*)A;
  const char* Bb = (const char*)Bt;
  const uint32_t rs = (uint32_t)K * 2;

  // fragment LDS byte offsets (loop-invariant; swizzle term is lane-const)
  uint32_t ra[2][4], rb[2][4];
  {
    const int sw = (lane & 7) << 4;
    const int gk = lane & 48;  // (lane>>4)*16 bytes = 8 bf16 k-chunk
#pragma unroll
    for (int kk = 0; kk < 2; ++kk) {
#pragma unroll
      for (int i = 0; i < 4; ++i) {
        uint32_t kb = (uint32_t)((kk * 64 + gk) ^ sw);
        ra[kk][i] = (uint32_t)(wm * 64 + i * 16 + (lane & 15)) * 128 + kb;
        rb[kk][i] = (uint32_t)(wn * 64 + i * 16 + (lane & 15)) * 128 + kb;
      }
    }
  }

  f32x4 acc[4][4];
#pragma unroll
  for (int i = 0; i < 4; ++i)
#pragma unroll
    for (int j = 0; j < 4; ++j) acc[i][j] = 0.0f;

  for (int k0 = 0; k0 < K; k0 += 64) {
    __syncthreads();  // previous compute done before LDS overwrite
    const uint32_t kbyte = (uint32_t)k0 * 2 + (uint32_t)scol;
#pragma unroll
    for (int i = 0; i < 4; ++i) {
      int row = i * 32 + srow;
      gload_lds16(Ab + (size_t)(bm0 + row) * rs + kbyte, ldsA + i * 4096 + slin);
    }
#pragma unroll
    for (int i = 0; i < 4; ++i) {
      int row = i * 32 + srow;
      gload_lds16(Bb + (size_t)(bn0 + row) * rs + kbyte, ldsB + i * 4096 + slin);
    }
    __syncthreads();  // compiler drains vmcnt before barrier -> tiles visible
#pragma unroll
    for (int kk = 0; kk < 2; ++kk) {
      bf16x8 af[4], bfv[4];
#pragma unroll
      for (int i = 0; i < 4; ++i) af[i] = *(const bf16x8*)(ldsA + ra[kk][i]);
#pragma unroll
      for (int i = 0; i < 4; ++i) bfv[i] = *(const bf16x8*)(ldsB + rb[kk][i]);
#pragma unroll
      for (int mi = 0; mi < 4; ++mi)
#pragma unroll
        for (int ni = 0; ni < 4; ++ni)
          acc[mi][ni] = mfma16(af[mi], bfv[ni], acc[mi][ni]);
    }
  }

  // C/D layout (verified m89/m91): col = lane&15, row = (lane>>4)*4 + reg
  const int r0 = (lane >> 4) * 4;
  const int cc = lane & 15;

  if constexpr (EPI == 0) {
    __bf16* O = (__bf16*)outp;
#pragma unroll
    for (int mi = 0; mi < 4; ++mi) {
#pragma unroll
      for (int ni = 0; ni < 4; ++ni) {
        int r = bm0 + wm * 64 + mi * 16 + r0;
        int c = bn0 + wn * 64 + ni * 16 + cc;
#pragma unroll
        for (int j = 0; j < 4; ++j)
          O[(size_t)(r + j) * N + c] = (__bf16)acc[mi][ni][j];
      }
    }
  } else if constexpr (EPI == 1) {
    float* O = (float*)outp;
#pragma unroll
    for (int mi = 0; mi < 4; ++mi) {
#pragma unroll
      for (int ni = 0; ni < 4; ++ni) {
        int r = bm0 + wm * 64 + mi * 16 + r0;
        int c = bn0 + wn * 64 + ni * 16 + cc;
        float bv = bias[c];
#pragma unroll
        for (int j = 0; j < 4; ++j)
          O[(size_t)(r + j) * N + c] = acc[mi][ni][j] + bv;
      }
    }
  } else {
    // per-row argmax over this wave's 64 cols -> partial (val, global col)
    const int nch = N >> 6;
#pragma unroll
    for (int mi = 0; mi < 4; ++mi) {
#pragma unroll
      for (int j = 0; j < 4; ++j) {
        float v = acc[mi][0][j];
        int c = cc;
#pragma unroll
        for (int ni = 1; ni < 4; ++ni) {
          float v2 = acc[mi][ni][j];
          int c2 = ni * 16 + cc;
          if (v2 > v) { v = v2; c = c2; }
        }
#pragma unroll
        for (int d = 1; d < 16; d <<= 1) {  // stays within 16-lane group
          float ov = __shfl_xor(v, d);
          int oc = __shfl_xor(c, d);
          if (ov > v || (ov == v && oc < c)) { v = ov; c = oc; }
        }
        if (cc == 0) {
          int r = bm0 + wm * 64 + mi * 16 + r0 + j;
          int chunk = (bn0 >> 6) + wn;
          part_val[r * nch + chunk] = v;
          part_idx[r * nch + chunk] = bn0 + wn * 64 + c;
        }
      }
    }
  }
}

// ---------------- LayerNorm + ReLU, in-place, one wave per 1024-row ----------------
__global__ __launch_bounds__(256) void k_ln_relu(__bf16* __restrict__ h,
                                                 const float* __restrict__ g,
                                                 const float* __restrict__ b) {
  int lane = threadIdx.x & 63;
  int row = blockIdx.x * 4 + (threadIdx.x >> 6);
  __bf16* rp = h + (size_t)row * 1024;
  bf16x8 v0 = *(const bf16x8*)(rp + lane * 8);
  bf16x8 v1 = *(const bf16x8*)(rp + 512 + lane * 8);
  float f0[8], f1[8];
  float s = 0.f, sq = 0.f;
#pragma unroll
  for (int j = 0; j < 8; ++j) {
    f0[j] = (float)v0[j]; f1[j] = (float)v1[j];
    s += f0[j] + f1[j];
    sq += f0[j] * f0[j] + f1[j] * f1[j];
  }
#pragma unroll
  for (int d = 1; d < 64; d <<= 1) { s += __shfl_xor(s, d); sq += __shfl_xor(sq, d); }
  float mu = s * (1.0f / 1024.0f);
  float var = sq * (1.0f / 1024.0f) - mu * mu;
  float rstd = rsqrtf(var + LN_EPS);
  const f32x4* gv = (const f32x4*)g;
  const f32x4* bv = (const f32x4*)b;
  f32x4 ga0 = gv[lane * 2], ga1 = gv[lane * 2 + 1];
  f32x4 gb0 = gv[128 + lane * 2], gb1 = gv[128 + lane * 2 + 1];
  f32x4 ba0 = bv[lane * 2], ba1 = bv[lane * 2 + 1];
  f32x4 bb0 = bv[128 + lane * 2], bb1 = bv[128 + lane * 2 + 1];
  bf16x8 o0, o1;
#pragma unroll
  for (int j = 0; j < 4; ++j) {
    float t0 = (f0[j] - mu) * rstd * ga0[j] + ba0[j];
    float t1 = (f0[j + 4] - mu) * rstd * ga1[j] + ba1[j];
    float t2 = (f1[j] - mu) * rstd * gb0[j] + bb0[j];
    float t3 = (f1[j + 4] - mu) * rstd * gb1[j] + bb1[j];
    o0[j] = (__bf16)fmaxf(t0, 0.f);
    o0[j + 4] = (__bf16)fmaxf(t1, 0.f);
    o1[j] = (__bf16)fmaxf(t2, 0.f);
    o1[j + 4] = (__bf16)fmaxf(t3, 0.f);
  }
  *(bf16x8*)(rp + lane * 8) = o0;
  *(bf16x8*)(rp + 512 + lane * 8) = o1;
}

// ---------------- log-softmax over D=256, one wave per row ----------------
__global__ __launch_bounds__(256) void k_softmax(const float* __restrict__ z,
                                                 float* __restrict__ p,
                                                 __bf16* __restrict__ ep) {
  int lane = threadIdx.x & 63;
  int row = blockIdx.x * 4 + (threadIdx.x >> 6);
  f32x4 v = ((const f32x4*)(z + (size_t)row * 256))[lane];
  float m = fmaxf(fmaxf(v[0], v[1]), fmaxf(v[2], v[3]));
#pragma unroll
  for (int d = 1; d < 64; d <<= 1) m = fmaxf(m, __shfl_xor(m, d));
  f32x4 e;
  float s = 0.f;
#pragma unroll
  for (int j = 0; j < 4; ++j) { e[j] = expf(v[j] - m); s += e[j]; }
#pragma unroll
  for (int d = 1; d < 64; d <<= 1) s += __shfl_xor(s, d);
  float ls = logf(s);
  float inv = 1.0f / s;
  f32x4 pv;
  bf16x4 ev;
#pragma unroll
  for (int j = 0; j < 4; ++j) { pv[j] = v[j] - m - ls; ev[j] = (__bf16)(e[j] * inv); }
  ((f32x4*)(p + (size_t)row * 256))[lane] = pv;
  ((bf16x4*)(ep + (size_t)row * 256))[lane] = ev;
}

// ---------------- finalize: argmax reduce, gather q, fp32 kl, block loss ----------------
__global__ __launch_bounds__(256) void k_final(
    const float* __restrict__ part_val, const int* __restrict__ part_idx,
    const float* __restrict__ p, const float* __restrict__ emb,
    const float* __restrict__ masks, float* __restrict__ q,
    float* __restrict__ blockloss) {
  __shared__ float ls[4];
  int lane = threadIdx.x & 63;
  int w = threadIdx.x >> 6;
  int row = blockIdx.x * 4 + w;
  float v = -3.4e38f;
  int c = 0x7fffffff;
  if (lane < 16) { v = part_val[row * 16 + lane]; c = part_idx[row * 16 + lane]; }
#pragma unroll
  for (int d = 1; d < 16; d <<= 1) {
    float ov = __shfl_xor(v, d);
    int oc = __shfl_xor(c, d);
    if (ov > v || (ov == v && oc < c)) { v = ov; c = oc; }
  }
  int code = __shfl(c, 0);
  f32x4 ev = ((const f32x4*)(emb + (size_t)code * 256))[lane];
  ((f32x4*)(q + (size_t)row * 256))[lane] = ev;  // q == quant (STE value)
  f32x4 pv = ((const f32x4*)(p + (size_t)row * 256))[lane];
  float kl = 0.f;
#pragma unroll
  for (int j = 0; j < 4; ++j) kl += expf(pv[j]) * (pv[j] - logf(ev[j]));
#pragma unroll
  for (int d = 1; d < 64; d <<= 1) kl += __shfl_xor(kl, d);
  if (lane == 0) ls[w] = kl * masks[row];
  __syncthreads();
  if (threadIdx.x == 0) blockloss[blockIdx.x] = ls[0] + ls[1] + ls[2] + ls[3];
}

// deterministic fixed-order final reduce (no float atomics)
__global__ __launch_bounds__(256) void k_loss_reduce(const float* __restrict__ bl,
                                                     float* __restrict__ out) {
  __shared__ float s[256];
  float a = 0.f;
#pragma unroll
  for (int i = 0; i < 16; ++i) a += bl[threadIdx.x + i * 256];
  s[threadIdx.x] = a;
  __syncthreads();
  for (int st = 128; st > 0; st >>= 1) {
    if (threadIdx.x < st) s[threadIdx.x] += s[threadIdx.x + st];
    __syncthreads();
  }
  if (threadIdx.x == 0) out[0] = s[0] * (0.25f / 16.0f);
}

// ---------------- launch ----------------
extern "C" void kernel_launch(void* const* d_in, const int* in_sizes, int n_in,
                              void* d_out, int out_size, void* d_ws, size_t ws_size,
                              hipStream_t stream) {
  const float* x = (const float*)d_in[0];
  const float* masks = (const float*)d_in[1];
  const float* W1 = (const float*)d_in[2];
  const float* g1 = (const float*)d_in[3];
  const float* b1 = (const float*)d_in[4];
  const float* W2 = (const float*)d_in[5];
  const float* g2 = (const float*)d_in[6];
  const float* b2 = (const float*)d_in[7];
  const float* W3 = (const float*)d_in[8];
  const float* g3 = (const float*)d_in[9];
  const float* b3 = (const float*)d_in[10];
  const float* W4 = (const float*)d_in[11];
  const float* g4 = (const float*)d_in[12];
  const float* b4 = (const float*)d_in[13];
  const float* W5 = (const float*)d_in[14];
  const float* b5 = (const float*)d_in[15];
  const float* emb = (const float*)d_in[16];

  const int M = 16384;  // B*T
  char* ws = (char*)d_ws;
  __bf16* bufA = (__bf16*)(ws);                       // 32 MB ping
  __bf16* bufB = (__bf16*)(ws + (32ull << 20));       // 32 MB pong (xb first)
  __bf16* W1t = (__bf16*)(ws + (64ull << 20));        // 1 MB  [1024][512]
  __bf16* W2t = (__bf16*)(ws + (65ull << 20));        // 2 MB  [1024][1024]
  __bf16* W3t = (__bf16*)(ws + (67ull << 20));        // 2 MB
  __bf16* W4t = (__bf16*)(ws + (69ull << 20));        // 2 MB
  __bf16* W5t = (__bf16*)(ws + (71ull << 20));        // 0.5 MB [256][1024]
  __bf16* logE = (__bf16*)(ws + (72ull << 20));       // 0.5 MB [1024][256]
  float* part_val = (float*)(ws + (73ull << 20));     // 1 MB
  int* part_idx = (int*)(ws + (74ull << 20));         // 1 MB
  float* blockloss = (float*)(ws + (75ull << 20));    // 16 KB
  float* p = (float*)(ws);                            // 16 MB, aliases bufA (dead by then)
  __bf16* ep = (__bf16*)(ws + (16ull << 20));         // 8 MB, aliases bufA upper half

  float* z = (float*)d_out;                 // [16384][256]
  float* q = z + (size_t)M * 256;           // [16384][256]
  float* lossp = z + 2ull * M * 256;        // [1]

  dim3 tb32(32, 32);
  k_cvt_bf16<<<4096, 256, 0, stream>>>(x, bufB);
  k_transpose<<<dim3(32, 16), tb32, 0, stream>>>(W1, W1t, 512, 1024);
  k_transpose<<<dim3(32, 32), tb32, 0, stream>>>(W2, W2t, 1024, 1024);
  k_transpose<<<dim3(32, 32), tb32, 0, stream>>>(W3, W3t, 1024, 1024);
  k_transpose<<<dim3(32, 32), tb32, 0, stream>>>(W4, W4t, 1024, 1024);
  k_transpose<<<dim3(8, 32), tb32, 0, stream>>>(W5, W5t, 1024, 256);
  k_logE<<<1024, 256, 0, stream>>>(emb, logE);

  k_gemm<0><<<dim3(128, 8), 256, 0, stream>>>(bufB, W1t, bufA, nullptr, nullptr, nullptr, 1024, 512);
  k_ln_relu<<<4096, 256, 0, stream>>>(bufA, g1, b1);
  k_gemm<0><<<dim3(128, 8), 256, 0, stream>>>(bufA, W2t, bufB, nullptr, nullptr, nullptr, 1024, 1024);
  k_ln_relu<<<4096, 256, 0, stream>>>(bufB, g2, b2);
  k_gemm<0><<<dim3(128, 8), 256, 0, stream>>>(bufB, W3t, bufA, nullptr, nullptr, nullptr, 1024, 1024);
  k_ln_relu<<<4096, 256, 0, stream>>>(bufA, g3, b3);
  k_gemm<0><<<dim3(128, 8), 256, 0, stream>>>(bufA, W4t, bufB, nullptr, nullptr, nullptr, 1024, 1024);
  k_ln_relu<<<4096, 256, 0, stream>>>(bufB, g4, b4);
  k_gemm<1><<<dim3(128, 2), 256, 0, stream>>>(bufB, W5t, z, b5, nullptr, nullptr, 256, 1024);
  k_softmax<<<4096, 256, 0, stream>>>(z, p, ep);
  k_gemm<2><<<dim3(128, 8), 256, 0, stream>>>(ep, logE, nullptr, nullptr, part_val, part_idx, 1024, 256);
  k_final<<<4096, 256, 0, stream>>>(part_val, part_idx, p, emb, masks, q, blockloss);
  k_loss_reduce<<<1, 256, 0, stream>>>(blockloss, lossp);
}

// Round 2
// 273.408 us; speedup vs baseline: 1.1542x; 1.1542x over previous
//
#include <hip/hip_runtime.h>
#include <hip/hip_bf16.h>
#include <stdint.h>

typedef __attribute__((ext_vector_type(4))) float f32x4;
typedef __attribute__((ext_vector_type(8))) __bf16 bf16x8;
typedef __attribute__((ext_vector_type(4))) __bf16 bf16x4;

#define LN_EPS 1e-5f

// ---------------- helpers ----------------
__device__ __forceinline__ void gload_lds16(const void* g, void* l) {
  __builtin_amdgcn_global_load_lds(
      (__attribute__((address_space(1))) void*)(uintptr_t)g,
      (__attribute__((address_space(3))) void*)(uint32_t)(uintptr_t)l,
      16, 0, 0);
}

__device__ __forceinline__ f32x4 mfma16(bf16x8 a, bf16x8 b, f32x4 c) {
  return __builtin_amdgcn_mfma_f32_16x16x32_bf16(a, b, c, 0, 0, 0);
}

// ---------------- prep kernels ----------------
__global__ __launch_bounds__(256) void k_cvt_bf16(const float* __restrict__ x,
                                                  __bf16* __restrict__ o) {
  int i = (blockIdx.x * 256 + threadIdx.x) * 8;
  f32x4 a = *(const f32x4*)(x + i);
  f32x4 b = *(const f32x4*)(x + i + 4);
  bf16x8 v;
#pragma unroll
  for (int j = 0; j < 4; ++j) { v[j] = (__bf16)a[j]; v[j + 4] = (__bf16)b[j]; }
  *(bf16x8*)(o + i) = v;
}

// W [K][N] f32 -> Wt [N][K] bf16
__global__ void k_transpose(const float* __restrict__ W, __bf16* __restrict__ Wt,
                            int K, int N) {
  __shared__ float t[32][33];
  int nt = blockIdx.x * 32, kt = blockIdx.y * 32;
  int tx = threadIdx.x, ty = threadIdx.y;
  t[ty][tx] = W[(size_t)(kt + ty) * N + nt + tx];
  __syncthreads();
  Wt[(size_t)(nt + ty) * K + kt + tx] = (__bf16)t[tx][ty];
}

// three same-shape 1024x1024 transposes in one launch (blockIdx.z selects)
__global__ void k_transpose3(const float* __restrict__ Wa, const float* __restrict__ Wb,
                             const float* __restrict__ Wc, __bf16* __restrict__ Ta,
                             __bf16* __restrict__ Tb, __bf16* __restrict__ Tc) {
  __shared__ float t[32][33];
  const float* W = blockIdx.z == 0 ? Wa : (blockIdx.z == 1 ? Wb : Wc);
  __bf16* T = blockIdx.z == 0 ? Ta : (blockIdx.z == 1 ? Tb : Tc);
  int nt = blockIdx.x * 32, kt = blockIdx.y * 32;
  int tx = threadIdx.x, ty = threadIdx.y;
  t[ty][tx] = W[(size_t)(kt + ty) * 1024 + nt + tx];
  __syncthreads();
  T[(size_t)(nt + ty) * 1024 + kt + tx] = (__bf16)t[tx][ty];
}

// centered log-embedding: log(E*256) (argmax-invariant shift keeps bf16 resolution)
__global__ __launch_bounds__(256) void k_logE(const float* __restrict__ e,
                                              __bf16* __restrict__ o) {
  int i = blockIdx.x * 256 + threadIdx.x;
  o[i] = (__bf16)logf(e[i] * 256.0f);
}

// ============ 256x256 deep-pipelined GEMM: C[M][N] = A[M][K] * Bt[N][K]^T ============
// BK=64, 8 waves (2Mx4N), per-wave out 128x64, 128 KiB LDS dbuf, 4 phases/K-tile.
// Counted vmcnt(4) once per K-tile (T4); setprio around MFMA (T5); conflict-free
// XOR swizzle col^=(row&7)<<4 via pre-swizzled global source (rule #21).
// Staging schedule (per tile t): p0: A(t+1).h0 -> other buf; p1: A(t+1).h1 +
// B(t+2).h0 -> cur.B (read-complete at p0); p2: B(t+2).h1. Requires K >= 256.
__global__ __launch_bounds__(512, 2) void k_gemm256(
    const __bf16* __restrict__ A, const __bf16* __restrict__ Bt,
    __bf16* __restrict__ O, int N, int K) {
  __shared__ char lds[131072];
  const int tid = threadIdx.x;
  const int lane = tid & 63;
  const int wid = tid >> 6;
  const int wm = wid >> 2;   // 0..1
  const int wn = wid & 3;    // 0..3
  const int bm0 = blockIdx.x * 256;
  const int bn0 = blockIdx.y * 256;
  const int NT = K >> 6;

  // staging addressing: thread covers 16B at linear LDS offset slin (+8192 2nd round)
  const int slin = tid * 16;
  const int lrow = slin >> 7;                          // 0..63 within half-tile
  const int scol = (slin & 127) ^ ((lrow & 7) << 4);   // pre-swizzled source col
  const char* Ab = (const char*)A;
  const char* Bb = (const char*)Bt;
  const uint32_t rs = (uint32_t)K * 2;

  // fragment LDS offsets
  const int klo = (lane >> 4) * 16;
  const int sw = (lane & 7) << 4;
  const uint32_t kx0 = (uint32_t)(klo ^ sw);
  const uint32_t kx1 = (uint32_t)((64 + klo) ^ sw);
  const uint32_t abase = (uint32_t)(wm * 128 + (lane & 15)) * 128;
  const uint32_t bbase = (uint32_t)(wn * 64 + (lane & 15)) * 128;

  f32x4 acc[8][4];
#pragma unroll
  for (int i = 0; i < 8; ++i)
#pragma unroll
    for (int j = 0; j < 4; ++j) acc[i][j] = 0.0f;

#define LDSA(buf) (lds + (buf)*32768)
#define LDSB(buf) (lds + 65536 + (buf)*32768)
#define STAGE_A(t, h)                                                              \
  {                                                                                \
    const char* src = Ab + (size_t)(bm0 + (h)*128 + lrow) * rs + ((t) << 7) + scol;\
    char* dst = LDSA((t)&1) + (h)*16384 + slin;                                    \
    gload_lds16(src, dst);                                                         \
    gload_lds16(src + (size_t)64 * rs, dst + 8192);                                \
  }
#define STAGE_B(t, h)                                                              \
  {                                                                                \
    const char* src = Bb + (size_t)(bn0 + (h)*128 + lrow) * rs + ((t) << 7) + scol;\
    char* dst = LDSB((t)&1) + (h)*16384 + slin;                                    \
    gload_lds16(src, dst);                                                         \
    gload_lds16(src + (size_t)64 * rs, dst + 8192);                                \
  }

  // prologue: tile0 fully + tile1's B halves; vmcnt(4) leaves t1.B in flight
  STAGE_A(0, 0); STAGE_A(0, 1); STAGE_B(0, 0); STAGE_B(0, 1);
  STAGE_B(1, 0); STAGE_B(1, 1);
  asm volatile("s_waitcnt vmcnt(4)" ::: "memory");
  __builtin_amdgcn_s_barrier();
  asm volatile("" ::: "memory");

  for (int t = 0; t < NT; ++t) {
    const char* Acur = LDSA(t & 1);
    const char* Bcur = LDSB(t & 1);
    bf16x8 bF[4][2];
#pragma unroll
    for (int p = 0; p < 4; ++p) {
      // ---- ds reads for this phase ----
      const uint32_t ar = abase + (uint32_t)(2 * p) * 2048;
      bf16x8 a00 = *(const bf16x8*)(Acur + ar + kx0);
      bf16x8 a01 = *(const bf16x8*)(Acur + ar + kx1);
      bf16x8 a10 = *(const bf16x8*)(Acur + ar + 2048 + kx0);
      bf16x8 a11 = *(const bf16x8*)(Acur + ar + 2048 + kx1);
      if (p == 0) {
#pragma unroll
        for (int ni = 0; ni < 4; ++ni) {
          bF[ni][0] = *(const bf16x8*)(Bcur + bbase + ni * 2048 + kx0);
          bF[ni][1] = *(const bf16x8*)(Bcur + bbase + ni * 2048 + kx1);
        }
      }
      // ---- prefetch staging (issue-early, lands tiles ahead) ----
      if (p == 0 && t + 1 < NT) STAGE_A(t + 1, 0);
      if (p == 1) {
        if (t + 1 < NT) STAGE_A(t + 1, 1);
        if (t + 2 < NT) STAGE_B(t + 2, 0);
      }
      if (p == 2 && t + 2 < NT) STAGE_B(t + 2, 1);

      asm volatile("" ::: "memory");
      __builtin_amdgcn_s_barrier();
      asm volatile("" ::: "memory");
      __builtin_amdgcn_s_setprio(1);
#pragma unroll
      for (int ni = 0; ni < 4; ++ni) {
        acc[2 * p][ni] = mfma16(a00, bF[ni][0], acc[2 * p][ni]);
        acc[2 * p][ni] = mfma16(a01, bF[ni][1], acc[2 * p][ni]);
        acc[2 * p + 1][ni] = mfma16(a10, bF[ni][0], acc[2 * p + 1][ni]);
        acc[2 * p + 1][ni] = mfma16(a11, bF[ni][1], acc[2 * p + 1][ni]);
      }
      __builtin_amdgcn_s_setprio(0);
      if (p == 3) asm volatile("s_waitcnt vmcnt(4)" ::: "memory");
      asm volatile("" ::: "memory");
      __builtin_amdgcn_s_barrier();
      asm volatile("" ::: "memory");
    }
  }
#undef STAGE_A
#undef STAGE_B
#undef LDSA
#undef LDSB

  // epilogue: C/D layout col=lane&15, row=(lane>>4)*4+reg
  const int r0 = (lane >> 4) * 4;
  const int cc = lane & 15;
#pragma unroll
  for (int mi = 0; mi < 8; ++mi) {
#pragma unroll
    for (int ni = 0; ni < 4; ++ni) {
      int r = bm0 + wm * 128 + mi * 16 + r0;
      int c = bn0 + wn * 64 + ni * 16 + cc;
#pragma unroll
      for (int j = 0; j < 4; ++j)
        O[(size_t)(r + j) * N + c] = (__bf16)acc[mi][ni][j];
    }
  }
}

// ---------------- 128x128 GEMM (kept for G5 bias-epilogue and G6 argmax) ----------------
template <int EPI>
__global__ __launch_bounds__(256) void k_gemm(
    const __bf16* __restrict__ A, const __bf16* __restrict__ Bt,
    void* __restrict__ outp, const float* __restrict__ bias,
    float* __restrict__ part_val, int* __restrict__ part_idx,
    int N, int K) {
  __shared__ char lds[32768];
  char* ldsA = lds;
  char* ldsB = lds + 16384;
  const int tid = threadIdx.x;
  const int lane = tid & 63;
  const int wid = tid >> 6;
  const int wm = wid >> 1, wn = wid & 1;
  const int bm0 = blockIdx.x * 128;
  const int bn0 = blockIdx.y * 128;

  const int slin = tid * 16;
  const int srow = slin >> 7;
  const int scol = (slin & 127) ^ ((srow & 7) << 4);

  const char* Ab = (const char*)A;
  const char* Bb = (const char*)Bt;
  const uint32_t rs = (uint32_t)K * 2;

  uint32_t ra[2][4], rb[2][4];
  {
    const int sw = (lane & 7) << 4;
    const int gk = lane & 48;
#pragma unroll
    for (int kk = 0; kk < 2; ++kk) {
#pragma unroll
      for (int i = 0; i < 4; ++i) {
        uint32_t kb = (uint32_t)((kk * 64 + gk) ^ sw);
        ra[kk][i] = (uint32_t)(wm * 64 + i * 16 + (lane & 15)) * 128 + kb;
        rb[kk][i] = (uint32_t)(wn * 64 + i * 16 + (lane & 15)) * 128 + kb;
      }
    }
  }

  f32x4 acc[4][4];
#pragma unroll
  for (int i = 0; i < 4; ++i)
#pragma unroll
    for (int j = 0; j < 4; ++j) acc[i][j] = 0.0f;

  for (int k0 = 0; k0 < K; k0 += 64) {
    __syncthreads();
    const uint32_t kbyte = (uint32_t)k0 * 2 + (uint32_t)scol;
#pragma unroll
    for (int i = 0; i < 4; ++i) {
      int row = i * 32 + srow;
      gload_lds16(Ab + (size_t)(bm0 + row) * rs + kbyte, ldsA + i * 4096 + slin);
    }
#pragma unroll
    for (int i = 0; i < 4; ++i) {
      int row = i * 32 + srow;
      gload_lds16(Bb + (size_t)(bn0 + row) * rs + kbyte, ldsB + i * 4096 + slin);
    }
    __syncthreads();
#pragma unroll
    for (int kk = 0; kk < 2; ++kk) {
      bf16x8 af[4], bfv[4];
#pragma unroll
      for (int i = 0; i < 4; ++i) af[i] = *(const bf16x8*)(ldsA + ra[kk][i]);
#pragma unroll
      for (int i = 0; i < 4; ++i) bfv[i] = *(const bf16x8*)(ldsB + rb[kk][i]);
#pragma unroll
      for (int mi = 0; mi < 4; ++mi)
#pragma unroll
        for (int ni = 0; ni < 4; ++ni)
          acc[mi][ni] = mfma16(af[mi], bfv[ni], acc[mi][ni]);
    }
  }

  const int r0 = (lane >> 4) * 4;
  const int cc = lane & 15;

  if constexpr (EPI == 1) {
    float* O = (float*)outp;
#pragma unroll
    for (int mi = 0; mi < 4; ++mi) {
#pragma unroll
      for (int ni = 0; ni < 4; ++ni) {
        int r = bm0 + wm * 64 + mi * 16 + r0;
        int c = bn0 + wn * 64 + ni * 16 + cc;
        float bv = bias[c];
#pragma unroll
        for (int j = 0; j < 4; ++j)
          O[(size_t)(r + j) * N + c] = acc[mi][ni][j] + bv;
      }
    }
  } else {
    const int nch = N >> 6;
#pragma unroll
    for (int mi = 0; mi < 4; ++mi) {
#pragma unroll
      for (int j = 0; j < 4; ++j) {
        float v = acc[mi][0][j];
        int c = cc;
#pragma unroll
        for (int ni = 1; ni < 4; ++ni) {
          float v2 = acc[mi][ni][j];
          int c2 = ni * 16 + cc;
          if (v2 > v) { v = v2; c = c2; }
        }
#pragma unroll
        for (int d = 1; d < 16; d <<= 1) {
          float ov = __shfl_xor(v, d);
          int oc = __shfl_xor(c, d);
          if (ov > v || (ov == v && oc < c)) { v = ov; c = oc; }
        }
        if (cc == 0) {
          int r = bm0 + wm * 64 + mi * 16 + r0 + j;
          int chunk = (bn0 >> 6) + wn;
          part_val[r * nch + chunk] = v;
          part_idx[r * nch + chunk] = bn0 + wn * 64 + c;
        }
      }
    }
  }
}

// ---------------- LayerNorm + ReLU, in-place, one wave per 1024-row ----------------
__global__ __launch_bounds__(256) void k_ln_relu(__bf16* __restrict__ h,
                                                 const float* __restrict__ g,
                                                 const float* __restrict__ b) {
  int lane = threadIdx.x & 63;
  int row = blockIdx.x * 4 + (threadIdx.x >> 6);
  __bf16* rp = h + (size_t)row * 1024;
  bf16x8 v0 = *(const bf16x8*)(rp + lane * 8);
  bf16x8 v1 = *(const bf16x8*)(rp + 512 + lane * 8);
  float f0[8], f1[8];
  float s = 0.f, sq = 0.f;
#pragma unroll
  for (int j = 0; j < 8; ++j) {
    f0[j] = (float)v0[j]; f1[j] = (float)v1[j];
    s += f0[j] + f1[j];
    sq += f0[j] * f0[j] + f1[j] * f1[j];
  }
#pragma unroll
  for (int d = 1; d < 64; d <<= 1) { s += __shfl_xor(s, d); sq += __shfl_xor(sq, d); }
  float mu = s * (1.0f / 1024.0f);
  float var = sq * (1.0f / 1024.0f) - mu * mu;
  float rstd = rsqrtf(var + LN_EPS);
  const f32x4* gv = (const f32x4*)g;
  const f32x4* bv = (const f32x4*)b;
  f32x4 ga0 = gv[lane * 2], ga1 = gv[lane * 2 + 1];
  f32x4 gb0 = gv[128 + lane * 2], gb1 = gv[128 + lane * 2 + 1];
  f32x4 ba0 = bv[lane * 2], ba1 = bv[lane * 2 + 1];
  f32x4 bb0 = bv[128 + lane * 2], bb1 = bv[128 + lane * 2 + 1];
  bf16x8 o0, o1;
#pragma unroll
  for (int j = 0; j < 4; ++j) {
    float t0 = (f0[j] - mu) * rstd * ga0[j] + ba0[j];
    float t1 = (f0[j + 4] - mu) * rstd * ga1[j] + ba1[j];
    float t2 = (f1[j] - mu) * rstd * gb0[j] + bb0[j];
    float t3 = (f1[j + 4] - mu) * rstd * gb1[j] + bb1[j];
    o0[j] = (__bf16)fmaxf(t0, 0.f);
    o0[j + 4] = (__bf16)fmaxf(t1, 0.f);
    o1[j] = (__bf16)fmaxf(t2, 0.f);
    o1[j + 4] = (__bf16)fmaxf(t3, 0.f);
  }
  *(bf16x8*)(rp + lane * 8) = o0;
  *(bf16x8*)(rp + 512 + lane * 8) = o1;
}

// ---------------- log-softmax over D=256, one wave per row ----------------
__global__ __launch_bounds__(256) void k_softmax(const float* __restrict__ z,
                                                 float* __restrict__ p,
                                                 __bf16* __restrict__ ep) {
  int lane = threadIdx.x & 63;
  int row = blockIdx.x * 4 + (threadIdx.x >> 6);
  f32x4 v = ((const f32x4*)(z + (size_t)row * 256))[lane];
  float m = fmaxf(fmaxf(v[0], v[1]), fmaxf(v[2], v[3]));
#pragma unroll
  for (int d = 1; d < 64; d <<= 1) m = fmaxf(m, __shfl_xor(m, d));
  f32x4 e;
  float s = 0.f;
#pragma unroll
  for (int j = 0; j < 4; ++j) { e[j] = expf(v[j] - m); s += e[j]; }
#pragma unroll
  for (int d = 1; d < 64; d <<= 1) s += __shfl_xor(s, d);
  float ls = logf(s);
  float inv = 1.0f / s;
  f32x4 pv;
  bf16x4 ev;
#pragma unroll
  for (int j = 0; j < 4; ++j) { pv[j] = v[j] - m - ls; ev[j] = (__bf16)(e[j] * inv); }
  ((f32x4*)(p + (size_t)row * 256))[lane] = pv;
  ((bf16x4*)(ep + (size_t)row * 256))[lane] = ev;
}

// ---------------- finalize: argmax reduce, gather q, fp32 kl, block loss ----------------
__global__ __launch_bounds__(256) void k_final(
    const float* __restrict__ part_val, const int* __restrict__ part_idx,
    const float* __restrict__ p, const float* __restrict__ emb,
    const float* __restrict__ masks, float* __restrict__ q,
    float* __restrict__ blockloss) {
  __shared__ float ls[4];
  int lane = threadIdx.x & 63;
  int w = threadIdx.x >> 6;
  int row = blockIdx.x * 4 + w;
  float v = -3.4e38f;
  int c = 0x7fffffff;
  if (lane < 16) { v = part_val[row * 16 + lane]; c = part_idx[row * 16 + lane]; }
#pragma unroll
  for (int d = 1; d < 16; d <<= 1) {
    float ov = __shfl_xor(v, d);
    int oc = __shfl_xor(c, d);
    if (ov > v || (ov == v && oc < c)) { v = ov; c = oc; }
  }
  int code = __shfl(c, 0);
  f32x4 ev = ((const f32x4*)(emb + (size_t)code * 256))[lane];
  ((f32x4*)(q + (size_t)row * 256))[lane] = ev;
  f32x4 pv = ((const f32x4*)(p + (size_t)row * 256))[lane];
  float kl = 0.f;
#pragma unroll
  for (int j = 0; j < 4; ++j) kl += expf(pv[j]) * (pv[j] - logf(ev[j]));
#pragma unroll
  for (int d = 1; d < 64; d <<= 1) kl += __shfl_xor(kl, d);
  if (lane == 0) ls[w] = kl * masks[row];
  __syncthreads();
  if (threadIdx.x == 0) blockloss[blockIdx.x] = ls[0] + ls[1] + ls[2] + ls[3];
}

__global__ __launch_bounds__(256) void k_loss_reduce(const float* __restrict__ bl,
                                                     float* __restrict__ out) {
  __shared__ float s[256];
  float a = 0.f;
#pragma unroll
  for (int i = 0; i < 16; ++i) a += bl[threadIdx.x + i * 256];
  s[threadIdx.x] = a;
  __syncthreads();
  for (int st = 128; st > 0; st >>= 1) {
    if (threadIdx.x < st) s[threadIdx.x] += s[threadIdx.x + st];
    __syncthreads();
  }
  if (threadIdx.x == 0) out[0] = s[0] * (0.25f / 16.0f);
}

// ---------------- launch ----------------
extern "C" void kernel_launch(void* const* d_in, const int* in_sizes, int n_in,
                              void* d_out, int out_size, void* d_ws, size_t ws_size,
                              hipStream_t stream) {
  const float* x = (const float*)d_in[0];
  const float* masks = (const float*)d_in[1];
  const float* W1 = (const float*)d_in[2];
  const float* g1 = (const float*)d_in[3];
  const float* b1 = (const float*)d_in[4];
  const float* W2 = (const float*)d_in[5];
  const float* g2 = (const float*)d_in[6];
  const float* b2 = (const float*)d_in[7];
  const float* W3 = (const float*)d_in[8];
  const float* g3 = (const float*)d_in[9];
  const float* b3 = (const float*)d_in[10];
  const float* W4 = (const float*)d_in[11];
  const float* g4 = (const float*)d_in[12];
  const float* b4 = (const float*)d_in[13];
  const float* W5 = (const float*)d_in[14];
  const float* b5 = (const float*)d_in[15];
  const float* emb = (const float*)d_in[16];

  const int M = 16384;  // B*T
  char* ws = (char*)d_ws;
  __bf16* bufA = (__bf16*)(ws);                       // 32 MB ping
  __bf16* bufB = (__bf16*)(ws + (32ull << 20));       // 32 MB pong (xb first)
  __bf16* W1t = (__bf16*)(ws + (64ull << 20));        // 1 MB  [1024][512]
  __bf16* W2t = (__bf16*)(ws + (65ull << 20));        // 2 MB  [1024][1024]
  __bf16* W3t = (__bf16*)(ws + (67ull << 20));        // 2 MB
  __bf16* W4t = (__bf16*)(ws + (69ull << 20));        // 2 MB
  __bf16* W5t = (__bf16*)(ws + (71ull << 20));        // 0.5 MB [256][1024]
  __bf16* logE = (__bf16*)(ws + (72ull << 20));       // 0.5 MB [1024][256]
  float* part_val = (float*)(ws + (73ull << 20));     // 1 MB
  int* part_idx = (int*)(ws + (74ull << 20));         // 1 MB
  float* blockloss = (float*)(ws + (75ull << 20));    // 16 KB
  float* p = (float*)(ws);                            // 16 MB, aliases bufA (dead by then)
  __bf16* ep = (__bf16*)(ws + (16ull << 20));         // 8 MB, aliases bufA upper half

  float* z = (float*)d_out;                 // [16384][256]
  float* q = z + (size_t)M * 256;           // [16384][256]
  float* lossp = z + 2ull * M * 256;        // [1]

  dim3 tb32(32, 32);
  k_cvt_bf16<<<4096, 256, 0, stream>>>(x, bufB);
  k_transpose<<<dim3(32, 16), tb32, 0, stream>>>(W1, W1t, 512, 1024);
  k_transpose3<<<dim3(32, 32, 3), tb32, 0, stream>>>(W2, W3, W4, W2t, W3t, W4t);
  k_transpose<<<dim3(8, 32), tb32, 0, stream>>>(W5, W5t, 1024, 256);
  k_logE<<<1024, 256, 0, stream>>>(emb, logE);

  k_gemm256<<<dim3(64, 4), 512, 0, stream>>>(bufB, W1t, bufA, 1024, 512);
  k_ln_relu<<<4096, 256, 0, stream>>>(bufA, g1, b1);
  k_gemm256<<<dim3(64, 4), 512, 0, stream>>>(bufA, W2t, bufB, 1024, 1024);
  k_ln_relu<<<4096, 256, 0, stream>>>(bufB, g2, b2);
  k_gemm256<<<dim3(64, 4), 512, 0, stream>>>(bufB, W3t, bufA, 1024, 1024);
  k_ln_relu<<<4096, 256, 0, stream>>>(bufA, g3, b3);
  k_gemm256<<<dim3(64, 4), 512, 0, stream>>>(bufA, W4t, bufB, 1024, 1024);
  k_ln_relu<<<4096, 256, 0, stream>>>(bufB, g4, b4);
  k_gemm<1><<<dim3(128, 2), 256, 0, stream>>>(bufB, W5t, z, b5, nullptr, nullptr, 256, 1024);
  k_softmax<<<4096, 256, 0, stream>>>(z, p, ep);
  k_gemm<2><<<dim3(128, 8), 256, 0, stream>>>(ep, logE, nullptr, nullptr, part_val, part_idx, 1024, 256);
  k_final<<<4096, 256, 0, stream>>>(part_val, part_idx, p, emb, masks, q, blockloss);
  k_loss_reduce<<<1, 256, 0, stream>>>(blockloss, lossp);
}